// Round 1
// baseline (624.227 us; speedup 1.0000x reference)
//
#include <hip/hip_runtime.h>
#include <hip/hip_bf16.h>
#include <math.h>

#define FREQS 9
#define DATA_DIM 28
#define WIDTH 128
#define IN_DIM 82   // DATA_DIM + FREQS*3*2

// ws layout (ints):
// [0] nonzero-byte counter
// [1] flag: 1 = mask stored as 1-byte elements, 0 = 4-byte elements
// [64 .. 64+B)      per-ray counts
// [64+B .. 64+2B)   per-ray exclusive offsets

__global__ void k_zero(int* ws) { ws[0] = 0; }

__global__ void k_count_bytes(const unsigned int* __restrict__ mw, int nwords, int* ws) {
    int tid = blockIdx.x * blockDim.x + threadIdx.x;
    int stride = gridDim.x * blockDim.x;
    int c = 0;
    for (int i = tid; i < nwords; i += stride) {
        unsigned int w = mw[i];
        c += ((w & 0xffu) != 0) + (((w >> 8) & 0xffu) != 0) +
             (((w >> 16) & 0xffu) != 0) + ((w >> 24) != 0);
    }
    __shared__ int red[256];
    red[threadIdx.x] = c;
    __syncthreads();
    for (int off = 128; off > 0; off >>= 1) {
        if (threadIdx.x < off) red[threadIdx.x] += red[threadIdx.x + off];
        __syncthreads();
    }
    if (threadIdx.x == 0) atomicAdd(&ws[0], red[0]);
}

__global__ void k_set_flag(int* ws, int P) { ws[1] = (ws[0] == P) ? 1 : 0; }

__global__ void k_ray_count(const void* __restrict__ maskp, const int* __restrict__ wsflag,
                            int* __restrict__ cnt, int N) {
    int b = blockIdx.x;
    int lane = threadIdx.x;
    int fl = wsflag[0];
    const unsigned char* m8 = (const unsigned char*)maskp;
    const int* m32 = (const int*)maskp;
    int base = 0;
    for (int t = 0; t < N / 64; ++t) {
        int n = t * 64 + lane;
        int mv = fl ? (int)m8[(size_t)b * N + n] : m32[(size_t)b * N + n];
        unsigned long long bal = __ballot(mv != 0);
        base += __popcll(bal);
    }
    if (lane == 0) cnt[b] = base;
}

// single block of 1024 threads, Bn must be divisible by 1024
__global__ void k_scan(const int* __restrict__ cnt, int* __restrict__ roff, int Bn) {
    __shared__ int sums[1024];
    int tid = threadIdx.x;
    int per = Bn / 1024;
    int loc[8];
    int s = 0;
    for (int i = 0; i < per; ++i) { loc[i] = s; s += cnt[tid * per + i]; }
    sums[tid] = s;
    __syncthreads();
    for (int off = 1; off < 1024; off <<= 1) {
        int t = sums[tid];
        int v = (tid >= off) ? sums[tid - off] : 0;
        __syncthreads();
        sums[tid] = t + v;
        __syncthreads();
    }
    int excl = sums[tid] - s;
    for (int i = 0; i < per; ++i) roff[tid * per + i] = excl + loc[i];
}

// 256 threads = 4 waves = 4 rays per block
__global__ __launch_bounds__(256) void k_render(
    const float* __restrict__ rays_d, const float* __restrict__ intrs,
    const void* __restrict__ maskp, const float* __restrict__ data,
    const float* __restrict__ W1, const float* __restrict__ b1,
    const float* __restrict__ W2, const float* __restrict__ b2,
    const int* __restrict__ wsflag, const int* __restrict__ roff,
    float* __restrict__ out, int Bn, int N)
{
    int wid = threadIdx.x >> 6;
    int lane = threadIdx.x & 63;
    int b = blockIdx.x * 4 + wid;

    float* out_comp = out;
    float* out_alpha = out + (size_t)Bn * 3;

    __shared__ int nlist[4][256];

    int fl = wsflag[0];
    const unsigned char* m8 = (const unsigned char*)maskp;
    const int* m32 = (const int*)maskp;

    // Build list of masked sample positions; write alpha=0 for unmasked (exactly once).
    int base = 0;
    for (int t = 0; t < N / 64; ++t) {
        int n = t * 64 + lane;
        int mv = fl ? (int)m8[(size_t)b * N + n] : m32[(size_t)b * N + n];
        bool m = (mv != 0);
        unsigned long long bal = __ballot(m);
        int rank = __popcll(bal & ((1ull << lane) - 1ull));
        if (m) nlist[wid][base + rank] = n;
        else   out_alpha[(size_t)b * N + n] = 0.0f;
        base += __popcll(bal);
    }
    __syncthreads();
    int count = base;           // wave-uniform
    int poff = roff[b];

    float dxv = rays_d[b * 3 + 0], dyv = rays_d[b * 3 + 1], dzv = rays_d[b * 3 + 2];
    float nrm = sqrtf(dxv * dxv + dyv * dyv + dzv * dzv);

    // mlp input: x[0..27] = data row, x[28..81] = positional encoding (per-ray, constant)
    float x[IN_DIM];
    #pragma unroll
    for (int f = 0; f < FREQS; ++f) {
        float sc = (float)(1 << f);
        float s0, c0, s1, c1, s2, c2;
        sincosf(dxv * sc, &s0, &c0);
        sincosf(dyv * sc, &s1, &c1);
        sincosf(dzv * sc, &s2, &c2);
        x[DATA_DIM + f * 6 + 0] = s0;
        x[DATA_DIM + f * 6 + 1] = s1;
        x[DATA_DIM + f * 6 + 2] = s2;
        x[DATA_DIM + f * 6 + 3] = c0;
        x[DATA_DIM + f * 6 + 4] = c1;
        x[DATA_DIM + f * 6 + 5] = c2;
    }

    float T = 1.0f;
    float aR = 0.f, aG = 0.f, aB = 0.f, aA = 0.f;

    for (int r0 = 0; r0 < count; r0 += 64) {
        int r = r0 + lane;
        bool act = (r < count);
        int n = act ? nlist[wid][r] : 0;

        if (act) {
            const float4* drow = (const float4*)(data + (size_t)(poff + r) * DATA_DIM);
            #pragma unroll
            for (int q = 0; q < 7; ++q) {
                float4 v = drow[q];
                x[q * 4 + 0] = v.x; x[q * 4 + 1] = v.y;
                x[q * 4 + 2] = v.z; x[q * 4 + 3] = v.w;
            }
        } else {
            #pragma unroll
            for (int q = 0; q < DATA_DIM; ++q) x[q] = 0.0f;
        }

        // MLP: h = relu(W1 x + b1) [128], preact = W2 h + b2 [4]
        float p0 = b2[0], p1 = b2[1], p2 = b2[2], p3 = b2[3];
        for (int j = 0; j < WIDTH; ++j) {
            const float* wr = W1 + j * IN_DIM;   // wave-uniform -> scalar loads
            float h0 = b1[j], h1 = 0.f, h2 = 0.f, h3 = 0.f;
            #pragma unroll
            for (int k = 0; k < 80; k += 4) {
                h0 = fmaf(wr[k + 0], x[k + 0], h0);
                h1 = fmaf(wr[k + 1], x[k + 1], h1);
                h2 = fmaf(wr[k + 2], x[k + 2], h2);
                h3 = fmaf(wr[k + 3], x[k + 3], h3);
            }
            h0 = fmaf(wr[80], x[80], h0);
            h1 = fmaf(wr[81], x[81], h1);
            float h = fmaxf((h0 + h1) + (h2 + h3), 0.0f);
            p0 = fmaf(W2[0 * WIDTH + j], h, p0);
            p1 = fmaf(W2[1 * WIDTH + j], h, p1);
            p2 = fmaf(W2[2 * WIDTH + j], h, p2);
            p3 = fmaf(W2[3 * WIDTH + j], h, p3);
        }

        float density = fmaxf(p0, 0.0f);
        float dist = (intrs[(size_t)b * (N + 1) + n + 1] - intrs[(size_t)b * (N + 1) + n]) * nrm;
        float alpha = act ? (1.0f - expf(-density * dist)) : 0.0f;

        // multiplicative exclusive scan of (1 - alpha + 1e-10) across the wave
        float fct = 1.0f - alpha + 1e-10f;
        float scan = fct;
        #pragma unroll
        for (int d = 1; d < 64; d <<= 1) {
            float o = __shfl_up(scan, d, 64);
            if (lane >= d) scan *= o;
        }
        float tot  = __shfl(scan, 63, 64);
        float excl = __shfl_up(scan, 1, 64);
        if (lane == 0) excl = 1.0f;

        float cum  = T * excl;
        float absl = alpha * cum;
        float sR = 1.0f / (1.0f + expf(-p1));
        float sG = 1.0f / (1.0f + expf(-p2));
        float sB = 1.0f / (1.0f + expf(-p3));
        aR = fmaf(absl, sR, aR);
        aG = fmaf(absl, sG, aG);
        aB = fmaf(absl, sB, aB);
        aA += absl;
        T *= tot;

        if (act) out_alpha[(size_t)b * N + n] = alpha;
    }

    #pragma unroll
    for (int d = 32; d > 0; d >>= 1) {
        aR += __shfl_down(aR, d, 64);
        aG += __shfl_down(aG, d, 64);
        aB += __shfl_down(aB, d, 64);
        aA += __shfl_down(aA, d, 64);
    }
    if (lane == 0) {
        out_comp[b * 3 + 0] = aR + (1.0f - aA);
        out_comp[b * 3 + 1] = aG + (1.0f - aA);
        out_comp[b * 3 + 2] = aB + (1.0f - aA);
    }
}

extern "C" void kernel_launch(void* const* d_in, const int* in_sizes, int n_in,
                              void* d_out, int out_size, void* d_ws, size_t ws_size,
                              hipStream_t stream) {
    const float* rays_d = (const float*)d_in[0];
    const float* intrs  = (const float*)d_in[1];
    const void*  maskp  = d_in[2];
    const float* data   = (const float*)d_in[3];
    const float* W1     = (const float*)d_in[4];
    const float* b1     = (const float*)d_in[5];
    const float* W2     = (const float*)d_in[6];
    const float* b2     = (const float*)d_in[7];
    float* out = (float*)d_out;

    int B = in_sizes[0] / 3;            // 8192
    int N = in_sizes[2] / B;            // 256
    int P = in_sizes[3] / DATA_DIM;     // packed sample count

    int* wsI  = (int*)d_ws;
    int* cnt  = wsI + 64;
    int* roff = wsI + 64 + B;

    k_zero<<<1, 1, 0, stream>>>(wsI);
    int nwords = (B * N) / 4;
    k_count_bytes<<<256, 256, 0, stream>>>((const unsigned int*)maskp, nwords, wsI);
    k_set_flag<<<1, 1, 0, stream>>>(wsI, P);
    k_ray_count<<<B, 64, 0, stream>>>(maskp, wsI + 1, cnt, N);
    k_scan<<<1, 1024, 0, stream>>>(cnt, roff, B);
    k_render<<<B / 4, 256, 0, stream>>>(rays_d, intrs, maskp, data, W1, b1, W2, b2,
                                        wsI + 1, roff, out, B, N);
}

// Round 2
// 223.123 us; speedup vs baseline: 2.7977x; 2.7977x over previous
//
#include <hip/hip_runtime.h>
#include <hip/hip_bf16.h>
#include <math.h>

#define FREQS 9
#define DATA_DIM 28
#define WIDTH 128
#define IN_DIM 82
#define KPAD 96

typedef float f32x4 __attribute__((ext_vector_type(4)));
typedef short s16x8 __attribute__((ext_vector_type(8)));

__device__ __forceinline__ short f2bf(float f) {
    unsigned u = __builtin_bit_cast(unsigned, f);
    u += 0x7fffu + ((u >> 16) & 1u);
    return (short)(u >> 16);
}

// ws layout (ints):
// [0] nonzero-byte counter, [1] mask-width flag
// [64 .. 64+B) per-ray counts ; [64+B .. 64+2B) exclusive offsets
// then W1bf (128*96 bf16 = 24576B), then W2T (128*4 f32 = 2048B)

__global__ void k_zero(int* ws) { ws[0] = 0; }

__global__ void k_count_bytes(const unsigned int* __restrict__ mw, int nwords, int* ws) {
    int tid = blockIdx.x * blockDim.x + threadIdx.x;
    int stride = gridDim.x * blockDim.x;
    int c = 0;
    for (int i = tid; i < nwords; i += stride) {
        unsigned int w = mw[i];
        c += ((w & 0xffu) != 0) + (((w >> 8) & 0xffu) != 0) +
             (((w >> 16) & 0xffu) != 0) + ((w >> 24) != 0);
    }
    __shared__ int red[256];
    red[threadIdx.x] = c;
    __syncthreads();
    for (int off = 128; off > 0; off >>= 1) {
        if (threadIdx.x < off) red[threadIdx.x] += red[threadIdx.x + off];
        __syncthreads();
    }
    if (threadIdx.x == 0) atomicAdd(&ws[0], red[0]);
}

__global__ void k_set_flag(int* ws, int P) { ws[1] = (ws[0] == P) ? 1 : 0; }

__global__ void k_ray_count(const void* __restrict__ maskp, const int* __restrict__ wsflag,
                            int* __restrict__ cnt, int N) {
    int b = blockIdx.x;
    int lane = threadIdx.x;
    int fl = wsflag[0];
    const unsigned char* m8 = (const unsigned char*)maskp;
    const int* m32 = (const int*)maskp;
    int base = 0;
    for (int t = 0; t < N / 64; ++t) {
        int n = t * 64 + lane;
        int mv = fl ? (int)m8[(size_t)b * N + n] : m32[(size_t)b * N + n];
        unsigned long long bal = __ballot(mv != 0);
        base += __popcll(bal);
    }
    if (lane == 0) cnt[b] = base;
}

__global__ void k_scan(const int* __restrict__ cnt, int* __restrict__ roff, int Bn) {
    __shared__ int sums[1024];
    int tid = threadIdx.x;
    int per = Bn / 1024;
    int loc[8];
    int s = 0;
    for (int i = 0; i < per; ++i) { loc[i] = s; s += cnt[tid * per + i]; }
    sums[tid] = s;
    __syncthreads();
    for (int off = 1; off < 1024; off <<= 1) {
        int t = sums[tid];
        int v = (tid >= off) ? sums[tid - off] : 0;
        __syncthreads();
        sums[tid] = t + v;
        __syncthreads();
    }
    int excl = sums[tid] - s;
    for (int i = 0; i < per; ++i) roff[tid * per + i] = excl + loc[i];
}

__global__ void k_prep(const float* __restrict__ W1, const float* __restrict__ W2,
                       short* __restrict__ W1bf, float* __restrict__ W2T) {
    int tid = blockIdx.x * blockDim.x + threadIdx.x;
    if (tid < WIDTH * KPAD) {
        int n = tid / KPAD, k = tid - n * KPAD;
        W1bf[tid] = (k < IN_DIM) ? f2bf(W1[n * IN_DIM + k]) : (short)0;
    }
    if (tid < WIDTH * 4) {
        int j = tid >> 2, o = tid & 3;
        W2T[tid] = W2[o * WIDTH + j];
    }
}

// one wave (64 threads) per ray
__global__ __launch_bounds__(64, 1) void k_render(
    const float* __restrict__ rays_d, const float* __restrict__ intrs,
    const void* __restrict__ maskp, const float* __restrict__ data,
    const short* __restrict__ W1bf, const float* __restrict__ b1,
    const float* __restrict__ W2T, const float* __restrict__ b2,
    const int* __restrict__ wsflag, const int* __restrict__ roff,
    float* __restrict__ out, int Bn, int N, int P)
{
    int lane = threadIdx.x;
    int b = blockIdx.x;
    int g = lane >> 4, c = lane & 15;

    float* out_comp = out;
    float* out_alpha = out + (size_t)Bn * 3;

    __shared__ int nlist[256];
    __shared__ __align__(16) float ppre[64][4];

    int fl = wsflag[0];
    const unsigned char* m8 = (const unsigned char*)maskp;
    const int* m32 = (const int*)maskp;

    // Phase 1: masked-n list; zero alpha for unmasked.
    int base = 0;
    for (int t = 0; t < N / 64; ++t) {
        int n = t * 64 + lane;
        int mv = fl ? (int)m8[(size_t)b * N + n] : m32[(size_t)b * N + n];
        bool m = (mv != 0);
        unsigned long long bal = __ballot(m);
        int rank = __popcll(bal & ((1ull << lane) - 1ull));
        if (m) nlist[base + rank] = n;
        else   out_alpha[(size_t)b * N + n] = 0.0f;
        base += __popcll(bal);
    }
    __syncthreads();
    int count = base;
    int poff = roff[b];

    float dx = rays_d[b * 3 + 0], dy = rays_d[b * 3 + 1], dz = rays_d[b * 3 + 2];
    float nrm = sqrtf(dx * dx + dy * dy + dz * dz);

    // Positional encoding, lane-parallel: pe[idx] on lane idx (idx<54).
    // layout: pe[f*6+t], t<3: sin(d[t]*2^f), t>=3: cos(d[t-3]*2^f)
    int idx = (lane < 54) ? lane : 0;
    int fb = idx / 6, t5 = idx - fb * 6;
    int ax = (t5 < 3) ? t5 : (t5 - 3);
    float dv = (ax == 0) ? dx : ((ax == 1) ? dy : dz);
    float ang = dv * (float)(1 << fb);
    float pev = (t5 < 3) ? sinf(ang) : cosf(ang);

    // Per-ray constant A-fragments for K-steps 1,2 (k=32..95 -> pe idx 4..67, >=54 zero)
    s16x8 aPE1, aPE2;
    short peT[4];
    #pragma unroll
    for (int j = 0; j < 8; ++j) {
        int i1 = 4 + 8 * g + j;
        aPE1[j] = f2bf(__shfl(pev, i1, 64));
        int i2 = 36 + 8 * g + j;
        float v2 = __shfl(pev, (i2 < 54) ? i2 : 0, 64);
        aPE2[j] = (i2 < 54) ? f2bf(v2) : (short)0;
    }
    #pragma unroll
    for (int j = 0; j < 4; ++j) peT[j] = f2bf(__shfl(pev, j, 64));  // k=28..31

    float b1v[8];
    #pragma unroll
    for (int nt = 0; nt < 8; ++nt) b1v[nt] = b1[16 * nt + c];
    f32x4 b2v = *reinterpret_cast<const f32x4*>(b2);

    const s16x8* W1v = reinterpret_cast<const s16x8*>(W1bf);

    float T = 1.0f;
    float aR = 0.f, aG = 0.f, aB = 0.f, aA = 0.f;

    for (int r0 = 0; r0 < count; r0 += 64) {
        int r = r0 + lane;
        bool act = (r < count);
        int n = act ? nlist[r] : 0;

        // A-fragments, K-step 0 (k=0..31): data cols 8g..8g+7 (g=3: cols 24..27 + pe tail)
        s16x8 a0[4];
        #pragma unroll
        for (int m = 0; m < 4; ++m) {
            int srow = poff + r0 + 16 * m + c;
            srow = (srow < P) ? srow : (P - 1);
            const float* dr = data + (size_t)srow * DATA_DIM;
            f32x4 lo = *reinterpret_cast<const f32x4*>(dr + 8 * g);
            #pragma unroll
            for (int j = 0; j < 4; ++j) a0[m][j] = f2bf(lo[j]);
            if (g < 3) {
                f32x4 hi = *reinterpret_cast<const f32x4*>(dr + 8 * g + 4);
                #pragma unroll
                for (int j = 0; j < 4; ++j) a0[m][4 + j] = f2bf(hi[j]);
            } else {
                #pragma unroll
                for (int j = 0; j < 4; ++j) a0[m][4 + j] = peT[j];
            }
        }

        f32x4 acc2v[4][4];
        #pragma unroll
        for (int m = 0; m < 4; ++m)
            #pragma unroll
            for (int q = 0; q < 4; ++q) acc2v[m][q] = (f32x4){0.f, 0.f, 0.f, 0.f};

        #pragma unroll
        for (int nt = 0; nt < 8; ++nt) {
            int nrow = 16 * nt + c;
            s16x8 B0 = W1v[nrow * 12 + g];
            s16x8 B1 = W1v[nrow * 12 + 4 + g];
            s16x8 B2 = W1v[nrow * 12 + 8 + g];

            f32x4 C0 = {0.f,0.f,0.f,0.f}, C1 = C0, C2 = C0, C3 = C0;
            C0 = __builtin_amdgcn_mfma_f32_16x16x32_bf16(a0[0], B0, C0, 0, 0, 0);
            C1 = __builtin_amdgcn_mfma_f32_16x16x32_bf16(a0[1], B0, C1, 0, 0, 0);
            C2 = __builtin_amdgcn_mfma_f32_16x16x32_bf16(a0[2], B0, C2, 0, 0, 0);
            C3 = __builtin_amdgcn_mfma_f32_16x16x32_bf16(a0[3], B0, C3, 0, 0, 0);
            C0 = __builtin_amdgcn_mfma_f32_16x16x32_bf16(aPE1, B1, C0, 0, 0, 0);
            C1 = __builtin_amdgcn_mfma_f32_16x16x32_bf16(aPE1, B1, C1, 0, 0, 0);
            C2 = __builtin_amdgcn_mfma_f32_16x16x32_bf16(aPE1, B1, C2, 0, 0, 0);
            C3 = __builtin_amdgcn_mfma_f32_16x16x32_bf16(aPE1, B1, C3, 0, 0, 0);
            C0 = __builtin_amdgcn_mfma_f32_16x16x32_bf16(aPE2, B2, C0, 0, 0, 0);
            C1 = __builtin_amdgcn_mfma_f32_16x16x32_bf16(aPE2, B2, C1, 0, 0, 0);
            C2 = __builtin_amdgcn_mfma_f32_16x16x32_bf16(aPE2, B2, C2, 0, 0, 0);
            C3 = __builtin_amdgcn_mfma_f32_16x16x32_bf16(aPE2, B2, C3, 0, 0, 0);

            f32x4 w2t = *reinterpret_cast<const f32x4*>(W2T + nrow * 4);
            f32x4 Cm[4] = {C0, C1, C2, C3};
            #pragma unroll
            for (int m = 0; m < 4; ++m)
                #pragma unroll
                for (int q = 0; q < 4; ++q) {
                    float h = fmaxf(Cm[m][q] + b1v[nt], 0.0f);
                    acc2v[m][q] += w2t * h;
                }
        }

        // reduce over c (low 4 lane bits): every lane gets full sums for its g
        #pragma unroll
        for (int m = 0; m < 4; ++m)
            #pragma unroll
            for (int q = 0; q < 4; ++q)
                #pragma unroll
                for (int comp = 0; comp < 4; ++comp) {
                    float v = acc2v[m][q][comp];
                    v += __shfl_xor(v, 1, 64);
                    v += __shfl_xor(v, 2, 64);
                    v += __shfl_xor(v, 4, 64);
                    v += __shfl_xor(v, 8, 64);
                    acc2v[m][q][comp] = v;
                }

        // scatter preact to LDS: row (sample-within-batch) = 16m + 4g + q, writer lane c == 4m+q
        #pragma unroll
        for (int m = 0; m < 4; ++m)
            #pragma unroll
            for (int q = 0; q < 4; ++q)
                if (c == 4 * m + q)
                    *reinterpret_cast<f32x4*>(&ppre[16 * m + 4 * g + q][0]) = acc2v[m][q];
        asm volatile("s_waitcnt lgkmcnt(0)" ::: "memory");
        f32x4 pr = *reinterpret_cast<const f32x4*>(&ppre[lane][0]);

        float p0 = pr[0] + b2v[0];
        float p1 = pr[1] + b2v[1];
        float p2 = pr[2] + b2v[2];
        float p3 = pr[3] + b2v[3];

        float density = fmaxf(p0, 0.0f);
        float dist = (intrs[(size_t)b * (N + 1) + n + 1] - intrs[(size_t)b * (N + 1) + n]) * nrm;
        float alpha = act ? (1.0f - expf(-density * dist)) : 0.0f;

        float fct = 1.0f - alpha + 1e-10f;
        float scan = fct;
        #pragma unroll
        for (int d = 1; d < 64; d <<= 1) {
            float o = __shfl_up(scan, d, 64);
            if (lane >= d) scan *= o;
        }
        float tot  = __shfl(scan, 63, 64);
        float excl = __shfl_up(scan, 1, 64);
        if (lane == 0) excl = 1.0f;

        float cum  = T * excl;
        float absl = alpha * cum;
        float sR = 1.0f / (1.0f + expf(-p1));
        float sG = 1.0f / (1.0f + expf(-p2));
        float sB = 1.0f / (1.0f + expf(-p3));
        aR = fmaf(absl, sR, aR);
        aG = fmaf(absl, sG, aG);
        aB = fmaf(absl, sB, aB);
        aA += absl;
        T *= tot;

        if (act) out_alpha[(size_t)b * N + n] = alpha;
    }

    #pragma unroll
    for (int d = 32; d > 0; d >>= 1) {
        aR += __shfl_down(aR, d, 64);
        aG += __shfl_down(aG, d, 64);
        aB += __shfl_down(aB, d, 64);
        aA += __shfl_down(aA, d, 64);
    }
    if (lane == 0) {
        out_comp[b * 3 + 0] = aR + (1.0f - aA);
        out_comp[b * 3 + 1] = aG + (1.0f - aA);
        out_comp[b * 3 + 2] = aB + (1.0f - aA);
    }
}

extern "C" void kernel_launch(void* const* d_in, const int* in_sizes, int n_in,
                              void* d_out, int out_size, void* d_ws, size_t ws_size,
                              hipStream_t stream) {
    const float* rays_d = (const float*)d_in[0];
    const float* intrs  = (const float*)d_in[1];
    const void*  maskp  = d_in[2];
    const float* data   = (const float*)d_in[3];
    const float* W1     = (const float*)d_in[4];
    const float* b1     = (const float*)d_in[5];
    const float* W2     = (const float*)d_in[6];
    const float* b2     = (const float*)d_in[7];
    float* out = (float*)d_out;

    int B = in_sizes[0] / 3;            // 8192
    int N = in_sizes[2] / B;            // 256
    int P = in_sizes[3] / DATA_DIM;     // packed sample count

    int* wsI   = (int*)d_ws;
    int* cnt   = wsI + 64;
    int* roff  = wsI + 64 + B;
    short* W1bf = (short*)(wsI + 64 + 2 * B);
    float* W2T  = (float*)(W1bf + WIDTH * KPAD);

    k_zero<<<1, 1, 0, stream>>>(wsI);
    int nwords = (B * N) / 4;
    k_count_bytes<<<256, 256, 0, stream>>>((const unsigned int*)maskp, nwords, wsI);
    k_set_flag<<<1, 1, 0, stream>>>(wsI, P);
    k_ray_count<<<B, 64, 0, stream>>>(maskp, wsI + 1, cnt, N);
    k_scan<<<1, 1024, 0, stream>>>(cnt, roff, B);
    k_prep<<<(WIDTH * KPAD + 255) / 256, 256, 0, stream>>>(W1, W2, W1bf, W2T);
    k_render<<<B, 64, 0, stream>>>(rays_d, intrs, maskp, data, W1bf, b1, W2T, b2,
                                   wsI + 1, roff, out, B, N, P);
}